// Round 4
// baseline (833.949 us; speedup 1.0000x reference)
//
#include <hip/hip_runtime.h>
#include <hip/hip_bf16.h>
#include <stdint.h>

#define IN_SZ 128
#define HID 128
#define OUT_SZ 67
#define SEQ 512
#define BATCH 2048
#define BT 16
#define NTHR 512
#define KTOT (IN_SZ + HID)
#define KPAD 260   // bf16/row: dword stride 130 == 2 mod 32 (measured 0 conflicts in R1/R3)

typedef __attribute__((ext_vector_type(4))) float f32x4;
typedef __attribute__((ext_vector_type(8))) short s16x8;
typedef __attribute__((ext_vector_type(4))) short s16x4;
typedef __attribute__((ext_vector_type(8))) __bf16 bf16x8;

// setup-only scalar RNE (not in hot loop)
static __device__ __forceinline__ unsigned short f2bf(float f) {
  union { float f; uint32_t u; } c; c.f = f;
  uint32_t u = c.u;
  uint32_t r = u + 0x7FFFu + ((u >> 16) & 1u);
  return (unsigned short)(r >> 16);
}
static __device__ __forceinline__ float bf2f(unsigned short h) {
  union { uint32_t u; float f; } c; c.u = ((uint32_t)h) << 16;
  return c.f;
}
// hot-loop packed convert: v_cvt_pk_bf16_f32 (lo -> low 16, hi -> high 16)
static __device__ __forceinline__ uint32_t pk2bf(float lo, float hi) {
  __hip_bfloat162 h2 = __float22bfloat162_rn(float2{lo, hi});
  union { __hip_bfloat162 h; uint32_t u; } c; c.h = h2;
  return c.u;
}

static __device__ __forceinline__ void mfma16(f32x4& c, s16x8 a, s16x8 b) {
  c = __builtin_amdgcn_mfma_f32_16x16x32_bf16(
        __builtin_bit_cast(bf16x8, a), __builtin_bit_cast(bf16x8, b), c, 0, 0, 0);
}

// barrier draining ONLY lgkmcnt (LDS), never vmcnt: x prefetch loads and Y
// stores float across steps.
static __device__ __forceinline__ void sync_lds() {
  __builtin_amdgcn_sched_barrier(0);
  asm volatile("s_waitcnt lgkmcnt(0)\n\ts_barrier" ::: "memory");
  __builtin_amdgcn_sched_barrier(0);
}

__global__ __launch_bounds__(NTHR, 2) void rnn_kernel(
    const float* __restrict__ x, const float* __restrict__ hidden,
    const float* __restrict__ mask, const float* __restrict__ Wi2h,
    const float* __restrict__ bi2h, const float* __restrict__ Wi2o,
    const float* __restrict__ bi2o, float* __restrict__ Y) {

  // Double-buffered C = [x_t ; h_{t-1}] (hi bf16 only). One barrier/step.
  // Window between barrier t-1 and t: reads hit buf p (i2h(t) + i2o(t-1)),
  // writes hit buf p^1 (h_t, x_{t+1}) -> race-free.
  __shared__ unsigned short sChi[2][BT][KPAD];

  const int tid = threadIdx.x;
  const int wave = tid >> 6;
  const int lane = tid & 63;
  const int g = lane >> 4;
  const int n16 = lane & 15;
  const int b0 = blockIdx.x * BT;

  // ---- Wi2h A-fragments, hi/lo split (weights stay split: cheap, setup-only)
  s16x8 wHi[8], wLo[8];
  {
    const float* wrow = Wi2h + (size_t)(16 * wave + n16) * KTOT;
#pragma unroll
    for (int kt = 0; kt < 8; ++kt) {
      s16x8 h8, l8;
#pragma unroll
      for (int j = 0; j < 8; ++j) {
        int k = 32 * kt + 4 * g + (j & 3) + ((j >> 2) << 4);
        float w = wrow[k];
        unsigned short hi = f2bf(w);
        h8[j] = (short)hi;
        l8[j] = (short)f2bf(w - bf2f(hi));
      }
      wHi[kt] = h8; wLo[kt] = l8;
    }
  }

  // ---- Wi2o A-fragments, waves 0..4, zero-padded rows >= 67
  s16x8 wO[4];
  if (wave < 5) {
    int m = 16 * wave + n16;
#pragma unroll
    for (int kt = 0; kt < 4; ++kt) {
      s16x8 o8;
#pragma unroll
      for (int j = 0; j < 8; ++j) {
        int k = 32 * kt + 4 * g + (j & 3) + ((j >> 2) << 4);
        float w = (m < OUT_SZ) ? Wi2o[(size_t)m * HID + k] : 0.f;
        o8[j] = (short)f2bf(w);
      }
      wO[kt] = o8;
    }
  }

  float bh[4], bo[4];
#pragma unroll
  for (int r = 0; r < 4; ++r) {
    int m = 16 * wave + 4 * g + r;
    bh[r] = bi2h[m];
    bo[r] = (wave < 5 && m < OUT_SZ) ? bi2o[m] : 0.f;
  }

  const int i = tid >> 2, bq = tid & 3;   // x stager: k-row i, 4 batch cols

  // ---- stage x_0 and h0 = hidden*mask into buf 0
  {
    const f32x4 xv = *(const f32x4*)(x + ((size_t)i * SEQ + 0) * BATCH + b0 + 4 * bq);
    uint32_t d0 = pk2bf(xv[0], xv[1]);
    uint32_t d1 = pk2bf(xv[2], xv[3]);
    sChi[0][4 * bq + 0][i] = (unsigned short)d0;
    sChi[0][4 * bq + 1][i] = (unsigned short)(d0 >> 16);
    sChi[0][4 * bq + 2][i] = (unsigned short)d1;
    sChi[0][4 * bq + 3][i] = (unsigned short)(d1 >> 16);
    const f32x4 hv = *(const f32x4*)(hidden + (size_t)i * BATCH + b0 + 4 * bq);
    const f32x4 mv = *(const f32x4*)(mask + (size_t)i * BATCH + b0 + 4 * bq);
    uint32_t e0 = pk2bf(hv[0] * mv[0], hv[1] * mv[1]);
    uint32_t e1 = pk2bf(hv[2] * mv[2], hv[3] * mv[3]);
    sChi[0][4 * bq + 0][IN_SZ + i] = (unsigned short)e0;
    sChi[0][4 * bq + 1][IN_SZ + i] = (unsigned short)(e0 >> 16);
    sChi[0][4 * bq + 2][IN_SZ + i] = (unsigned short)e1;
    sChi[0][4 * bq + 3][IN_SZ + i] = (unsigned short)(e1 >> 16);
  }
  sync_lds();

  // ---- x prefetch pointers (incremented, no per-step 64-bit recompute)
  const float* xbase = x + (size_t)i * SEQ * BATCH + b0 + 4 * bq;
  f32x4 xcur = *(const f32x4*)(xbase + (size_t)1 * BATCH);   // x_1
  const float* pref = xbase + (size_t)2 * BATCH;             // -> x_2

  // ---- Y row pointers for this lane (waves 0..4), col 0 initially
  float* yp[4];
  if (wave < 5) {
#pragma unroll
    for (int r = 0; r < 4; ++r) {
      int m = 16 * wave + 4 * g + r;
      yp[r] = (m < OUT_SZ) ? (Y + (size_t)m * SEQ * BATCH + b0 + n16) : nullptr;
    }
  }

  int p = 0;
  for (int t = 0; t < SEQ; ++t) {
    // prefetch x_{t+2} (clamped; t=510/511 re-load x_511, harmless)
    f32x4 xnext = *(const f32x4*)pref;
    if (t + 3 < SEQ) pref += BATCH;

    // ---- i2h(t): reads buf p ([x_t ; h_{t-1}])
    f32x4 accA = {0.f, 0.f, 0.f, 0.f};
    f32x4 accB = {0.f, 0.f, 0.f, 0.f};
#pragma unroll
    for (int kt = 0; kt < 8; ++kt) {
      const unsigned short* pp = &sChi[p][n16][32 * kt + 4 * g];
      s16x4 c0 = *(const s16x4*)pp;
      s16x4 c1 = *(const s16x4*)(pp + 16);
      s16x8 ch = __builtin_shufflevector(c0, c1, 0, 1, 2, 3, 4, 5, 6, 7);
      mfma16(accA, wHi[kt], ch);
      mfma16(accB, wLo[kt], ch);
    }

    // ---- i2o(t-1): independent MFMAs on buf p h-region; fills i2h stalls
    if (wave < 5 && t > 0) {
      f32x4 ao = {0.f, 0.f, 0.f, 0.f};
#pragma unroll
      for (int kt = 0; kt < 4; ++kt) {
        const unsigned short* pp = &sChi[p][n16][IN_SZ + 32 * kt + 4 * g];
        s16x4 c0 = *(const s16x4*)pp;
        s16x4 c1 = *(const s16x4*)(pp + 16);
        s16x8 ch = __builtin_shufflevector(c0, c1, 0, 1, 2, 3, 4, 5, 6, 7);
        mfma16(ao, wO[kt], ch);
      }
#pragma unroll
      for (int r = 0; r < 4; ++r) {
        if (yp[r]) {
          *yp[r] = fmaxf(ao[r] + bo[r], 0.f);
          yp[r] += BATCH;   // advance to col t
        }
      }
    }

    // ---- h_t = tanh(accA+accB+bh) -> buf p^1 (b64 write, conflict-free)
    {
      float th[4];
#pragma unroll
      for (int r = 0; r < 4; ++r) {
        float pre = accA[r] + accB[r] + bh[r];
        float e = __expf(2.f * pre);
        th[r] = 1.f - 2.f / (e + 1.f);
      }
      uint32_t d0 = pk2bf(th[0], th[1]);
      uint32_t d1 = pk2bf(th[2], th[3]);
      uint32_t hp[2] = {d0, d1};
      *(uint64_t*)&sChi[p ^ 1][n16][IN_SZ + 16 * wave + 4 * g] = *(uint64_t*)hp;
    }
    // ---- x_{t+1} -> buf p^1
    {
      uint32_t d0 = pk2bf(xcur[0], xcur[1]);
      uint32_t d1 = pk2bf(xcur[2], xcur[3]);
      sChi[p ^ 1][4 * bq + 0][i] = (unsigned short)d0;
      sChi[p ^ 1][4 * bq + 1][i] = (unsigned short)(d0 >> 16);
      sChi[p ^ 1][4 * bq + 2][i] = (unsigned short)d1;
      sChi[p ^ 1][4 * bq + 3][i] = (unsigned short)(d1 >> 16);
    }
    sync_lds();   // publish buf p^1 (LDS-only drain)

    xcur = xnext;
    p ^= 1;
  }

  // ---- epilogue: i2o for t = SEQ-1 (h_{511} now in buf p)
  if (wave < 5) {
    f32x4 ao = {0.f, 0.f, 0.f, 0.f};
#pragma unroll
    for (int kt = 0; kt < 4; ++kt) {
      const unsigned short* pp = &sChi[p][n16][IN_SZ + 32 * kt + 4 * g];
      s16x4 c0 = *(const s16x4*)pp;
      s16x4 c1 = *(const s16x4*)(pp + 16);
      s16x8 ch = __builtin_shufflevector(c0, c1, 0, 1, 2, 3, 4, 5, 6, 7);
      mfma16(ao, wO[kt], ch);
    }
#pragma unroll
    for (int r = 0; r < 4; ++r) {
      if (yp[r]) *yp[r] = fmaxf(ao[r] + bo[r], 0.f);
    }
  }
}

extern "C" void kernel_launch(void* const* d_in, const int* in_sizes, int n_in,
                              void* d_out, int out_size, void* d_ws, size_t ws_size,
                              hipStream_t stream) {
  const float* x      = (const float*)d_in[0];
  const float* hidden = (const float*)d_in[1];
  const float* mask   = (const float*)d_in[2];
  const float* Wi2h   = (const float*)d_in[3];
  const float* bi2h   = (const float*)d_in[4];
  const float* Wi2o   = (const float*)d_in[5];
  const float* bi2o   = (const float*)d_in[6];
  float* Y = (float*)d_out;
  (void)in_sizes; (void)n_in; (void)out_size; (void)d_ws; (void)ws_size;
  rnn_kernel<<<dim3(BATCH / BT), dim3(NTHR), 0, stream>>>(
      x, hidden, mask, Wi2h, bi2h, Wi2o, bi2o, Y);
}